// Round 4
// baseline (66.748 us; speedup 1.0000x reference)
//
#include <hip/hip_runtime.h>

// Problem constants (match reference)
#define BATCH 32
#define HW    3136   // 56*56  (3136 % 32 == 0 -> channel-major LDS, banks = r%32)
#define NCH   256
#define CHB   4      // channels per block: HW*CHB*4 = 50,176 B LDS
#define THREADS 1024

// ---------------------------------------------------------------------------
// LDS-staged per-channel spatial jumble, v3.
//   out[b,p,ch] = mask[ch] ? x[b, perm[ch,p], ch] : x[b,p,ch]
//
// v2 -> v3: CHB 8 -> 4 halves LDS to 50 KB so TWO 1024-thread blocks fit per
// CU (32 waves = 100% occupancy, was 41%), letting one block's gather overlap
// the other's staging (v2 had 1 block/CU -> phases hard-serialized).
//
// LDS is CHANNEL-MAJOR lds[c*HW + r]: HW % 32 == 0 so bank = r % 32; random
// perm rows spread ~uniformly (max ~6-way over 64 lanes, measured ~3.7 extra
// cyc/op in v2 -- acceptable). Staging writes are 2-lanes/bank = free.
//
// One gather thread = one pixel: 4 coalesced perm loads (256 B/wave, perm is
// L2-resident: 3.2 MB < 4 MiB/XCD), 4 LDS reads, one float4 store.
//
// Grid 2048 = 8 xcd x 4 batches x 64 chblks, chblk-INNER so the 4 chblk
// siblings sharing each 64B line of x/out run concurrently on one XCD.
// ---------------------------------------------------------------------------
__global__ __launch_bounds__(THREADS) void jumble_v3_kernel(
    const float* __restrict__ x, const float* __restrict__ mask,
    const int* __restrict__ perm, float* __restrict__ out) {
  __shared__ float lds[CHB * HW];  // 50,176 B

  const unsigned bid = blockIdx.x;
  const unsigned xcd = bid & 7u;           // hardware XCD of this block
  const unsigned l = bid >> 3u;            // 0..255 within xcd
  const unsigned chblk = l & 63u;          // chblk-inner
  const unsigned b = 4u * xcd + (l >> 6);  // 4 batches per xcd
  const unsigned ch0 = chblk * CHB;

  const unsigned t = threadIdx.x;

  // ---- stage x[b, :, ch0..ch0+3] into LDS (float4 reads, transposed store) ----
  const float4* __restrict__ xg4 =
      (const float4*)(x + (size_t)b * (HW * NCH) + ch0);
  for (unsigned p = t; p < HW; p += THREADS) {
    const float4 v = xg4[p * (NCH / 4)];
    lds[0 * HW + p] = v.x;  // banks = p%32, 2-way, free
    lds[1 * HW + p] = v.y;
    lds[2 * HW + p] = v.z;
    lds[3 * HW + p] = v.w;
  }

  // wave-uniform per-channel state (scalar regs)
  const int* __restrict__ pr0 = perm + (size_t)(ch0 + 0) * HW;
  const int* __restrict__ pr1 = perm + (size_t)(ch0 + 1) * HW;
  const int* __restrict__ pr2 = perm + (size_t)(ch0 + 2) * HW;
  const int* __restrict__ pr3 = perm + (size_t)(ch0 + 3) * HW;
  const bool m0 = mask[ch0 + 0] != 0.0f;
  const bool m1 = mask[ch0 + 1] != 0.0f;
  const bool m2 = mask[ch0 + 2] != 0.0f;
  const bool m3 = mask[ch0 + 3] != 0.0f;

  __syncthreads();

  // ---- gather from LDS, one pixel per thread, float4 store ----
  float4* __restrict__ og4 = (float4*)(out + (size_t)b * (HW * NCH) + ch0);
  for (unsigned p = t; p < HW; p += THREADS) {
    const int r0 = m0 ? pr0[p] : (int)p;  // coalesced 256B/wave each
    const int r1 = m1 ? pr1[p] : (int)p;
    const int r2 = m2 ? pr2[p] : (int)p;
    const int r3 = m3 ? pr3[p] : (int)p;
    float4 v;
    v.x = lds[0 * HW + r0];  // banks = r%32, ~random (max ~6-way)
    v.y = lds[1 * HW + r1];
    v.z = lds[2 * HW + r2];
    v.w = lds[3 * HW + r3];
    og4[p * (NCH / 4)] = v;
  }
}

extern "C" void kernel_launch(void* const* d_in, const int* in_sizes, int n_in,
                              void* d_out, int out_size, void* d_ws, size_t ws_size,
                              hipStream_t stream) {
  const float* x = (const float*)d_in[0];
  const float* mask = (const float*)d_in[1];
  const int* perm = (const int*)d_in[2];
  float* out = (float*)d_out;

  jumble_v3_kernel<<<BATCH * (NCH / CHB), THREADS, 0, stream>>>(
      x, mask, perm, out);
}